// Round 6
// baseline (206.271 us; speedup 1.0000x reference)
//
#include <hip/hip_runtime.h>
#include <stdint.h>

typedef __attribute__((ext_vector_type(8))) short short8;
typedef __attribute__((ext_vector_type(4))) short bf16x4;
typedef __attribute__((ext_vector_type(4))) float f32x4;

#define MFMA32(a, b, c) __builtin_amdgcn_mfma_f32_16x16x32_bf16((a), (b), (c), 0, 0, 0)
#define MFMA16(a, b, c) __builtin_amdgcn_mfma_f32_16x16x16bf16_1k((a), (b), (c), 0, 0, 0)

__device__ __forceinline__ uint16_t f32_to_bf16(float f) {
  union { float f; uint32_t u; } v; v.f = f;
  uint32_t u = v.u;
  u += 0x7FFFu + ((u >> 16) & 1u);   // RTNE
  return (uint16_t)(u >> 16);
}
__device__ __forceinline__ uint16_t f32_to_bf16_fast(float f) {
  union { float f; uint32_t u; } v; v.f = f;
  return (uint16_t)((v.u + 0x8000u) >> 16);   // round-half-up (P only)
}

__device__ __forceinline__ void load_lds16(const uint16_t* g, uint16_t* l) {
  __builtin_amdgcn_global_load_lds(
      (const __attribute__((address_space(1))) uint32_t*)g,
      (__attribute__((address_space(3))) uint32_t*)l, 16, 0, 0);
}

// ---------------- fused f32 -> bf16 conversion (x, Wqkv, Wout) ----------------
__global__ __launch_bounds__(256) void cvt3_kernel(
    const float* __restrict__ x, const float* __restrict__ w1,
    const float* __restrict__ w2, uint16_t* __restrict__ xb,
    uint16_t* __restrict__ w1b, uint16_t* __restrict__ w2b) {
  const int i = blockIdx.x * 256 + threadIdx.x;  // 2,097,152 float4 total
  const float4* src;
  ushort4* dst;
  int off;
  if (i < 1048576) { src = (const float4*)x;  dst = (ushort4*)xb;  off = i; }
  else if (i < 1835008) { src = (const float4*)w1; dst = (ushort4*)w1b; off = i - 1048576; }
  else { src = (const float4*)w2; dst = (ushort4*)w2b; off = i - 1835008; }
  const float4 v = src[off];
  ushort4 o;
  o.x = f32_to_bf16(v.x);
  o.y = f32_to_bf16(v.y);
  o.z = f32_to_bf16(v.z);
  o.w = f32_to_bf16(v.w);
  dst[off] = o;
}

// ---------------- output-proj GEMM (old 128x128 structure, bias epilogue) ----------------
__global__ __launch_bounds__(256) void gemm_abt_kernel(
    const uint16_t* __restrict__ A, const uint16_t* __restrict__ Bt,
    float* __restrict__ Cf, const float* __restrict__ bias, int M, int N, int K) {
  __shared__ __align__(16) uint16_t As[128 * 32];
  __shared__ __align__(16) uint16_t Bs[128 * 32];
  const int tid = threadIdx.x;
  const int wave = tid >> 6;
  const int lane = tid & 63;
  const int quad = lane >> 4;
  const int l16 = lane & 15;
  const int row0 = blockIdx.x * 128;
  const int col0 = blockIdx.y * 128;
  const int wm = (wave >> 1) * 64;
  const int wn = (wave & 1) * 64;

  f32x4 acc[4][4];
#pragma unroll
  for (int a = 0; a < 4; ++a)
#pragma unroll
    for (int b = 0; b < 4; ++b) acc[a][b] = (f32x4){0.f, 0.f, 0.f, 0.f};

  const uint16_t* gA = A + (size_t)(row0 + wave * 32 + (lane >> 2)) * K + (lane & 3) * 8;
  const uint16_t* gB = Bt + (size_t)(col0 + wave * 32 + (lane >> 2)) * K + (lane & 3) * 8;
  uint16_t* lA = As + wave * 1024;
  uint16_t* lB = Bs + wave * 1024;

  for (int k0 = 0; k0 < K; k0 += 32) {
    load_lds16(gA, lA);
    load_lds16(gA + (size_t)16 * K, lA + 512);
    load_lds16(gB, lB);
    load_lds16(gB + (size_t)16 * K, lB + 512);
    gA += 32;
    gB += 32;
    __syncthreads();
    short8 af[4], bf[4];
#pragma unroll
    for (int mt = 0; mt < 4; ++mt)
      af[mt] = *(const short8*)&As[(wm + mt * 16 + l16) * 32 + quad * 8];
#pragma unroll
    for (int nt = 0; nt < 4; ++nt)
      bf[nt] = *(const short8*)&Bs[(wn + nt * 16 + l16) * 32 + quad * 8];
#pragma unroll
    for (int mt = 0; mt < 4; ++mt)
#pragma unroll
      for (int nt = 0; nt < 4; ++nt)
        acc[mt][nt] = MFMA32(af[mt], bf[nt], acc[mt][nt]);
    __syncthreads();
  }

#pragma unroll
  for (int mt = 0; mt < 4; ++mt) {
#pragma unroll
    for (int nt = 0; nt < 4; ++nt) {
      const int col = col0 + wn + nt * 16 + l16;
#pragma unroll
      for (int r = 0; r < 4; ++r) {
        const int row = row0 + wm + mt * 16 + quad * 4 + r;
        Cf[(size_t)row * N + col] = acc[mt][nt][r] + bias[col];
      }
    }
  }
}

// ---------------- QKV GEMM: 256x128 tile, BK=64, 3-slot counted-vmcnt pipeline ----------------
// R5 post-mortem: 2-slot + __syncthreads = vmcnt(0) drain at every barrier with
// 1 block/CU and lockstep waves -> ~85% stall (MfmaUtil 17%, conflicts already 0).
// T4 fix (the documented lever, m218: counted-vs-drain0 = +38..73%): 3 rotating
// slots; stage tile t+3 into the slot tile t vacated; before computing tile t
// wait vmcnt(12) = allow tiles t+1,t+2 (6 loads each) to STAY IN FLIGHT across
// the barrier. Tile t's loads were issued 3 iterations (~2000 cyc) earlier ->
// the wait is normally free; never vmcnt(0) in the main loop.
// Race proof: per iter = {vmcnt(12); barrier; compute slot t%3; barrier;
// stage t+3 -> slot t%3}. Post-compute barrier orders writes after ALL waves'
// reads; vmcnt+pre-compute barrier orders reads after ALL waves' loads landed
// (uniform per-wave issue order makes the per-wave count a global guarantee).
// LDS 144 KB (A 3x32K + B 3x16K), read/write swizzle verbatim from R5
// (measured 0 conflicts). setprio kept (phase-split now real, T5/m218b).
__global__ __launch_bounds__(512, 2) void gemm_qkv_kernel(
    const uint16_t* __restrict__ A, const uint16_t* __restrict__ Bt,
    uint16_t* __restrict__ Qh, uint16_t* __restrict__ Kh, uint16_t* __restrict__ Vh) {
  __shared__ __align__(16) uint16_t As3[3][256 * 64];   // 3 x 32 KB
  __shared__ __align__(16) uint16_t Bs3[3][128 * 64];   // 3 x 16 KB
  const int tid = threadIdx.x;
  const int wave = tid >> 6;
  const int lane = tid & 63;
  const int quad = lane >> 4;
  const int l16 = lane & 15;
  const int wr = wave >> 2;      // 0..1 (M half: 128 rows)
  const int wc = wave & 3;       // 0..3 (32-col group)
  const int row0 = blockIdx.x * 256;
  const int col0 = blockIdx.y * 128;
  const int K = 1024;

  f32x4 acc[8][2];
#pragma unroll
  for (int a = 0; a < 8; ++a)
#pragma unroll
    for (int b = 0; b < 2; ++b) acc[a][b] = (f32x4){0.f, 0.f, 0.f, 0.f};

  // staging: wave covers 8 rows per 64-row group; 8 lanes x 16 B = 128 B/row.
  // SOURCE chunk pre-swizzled (T2 write side, proven R5): chunk = (lane&7)^(row&7).
  const int swz8 = ((lane & 7) ^ ((lane >> 3) & 7)) * 8;
  const uint16_t* gA = A + (size_t)(row0 + wave * 8 + (lane >> 3)) * K + swz8;
  const uint16_t* gB = Bt + (size_t)(col0 + wave * 8 + (lane >> 3)) * K + swz8;
  const int ldsw = wave * 512;   // wave-uniform LDS dest (lane offset implicit)

  // tile t, row-group s: A rows [s*64, s*64+64), K-cols [t*64, t*64+64)
#define STAGEA(slot, t, s) \
  load_lds16(gA + (size_t)(s) * 64 * K + (size_t)(t) * 64, &As3[slot][(s) * 4096 + ldsw])
#define STAGEB(slot, t, s) \
  load_lds16(gB + (size_t)(s) * 64 * K + (size_t)(t) * 64, &Bs3[slot][(s) * 4096 + ldsw])
#define STAGE6(slot, t)                                          \
  do {                                                           \
    STAGEA(slot, t, 0); STAGEA(slot, t, 1);                      \
    STAGEA(slot, t, 2); STAGEA(slot, t, 3);                      \
    STAGEB(slot, t, 0); STAGEB(slot, t, 1);                      \
  } while (0)

  // prologue: tiles 0,1,2 -> slots 0,1,2 (issue order fixed: 6 loads per tile)
  STAGE6(0, 0);
  STAGE6(1, 1);
  STAGE6(2, 2);

  for (int t = 0; t < 16; ++t) {
    const int st = t % 3;
    // counted wait: allow tiles t+1,t+2 (12 loads) in flight; tile t landed.
    asm volatile("s_waitcnt vmcnt(12)" ::: "memory");
    __builtin_amdgcn_s_barrier();

    const uint16_t* as = As3[st];
    const uint16_t* bs = Bs3[st];
#pragma unroll
    for (int ks = 0; ks < 2; ++ks) {
      // read swizzle cancels the source pre-swizzle (row&7 == l16&7 here)
      const int cswz = (((ks * 4 + quad) ^ (l16 & 7)) * 8);
      const short8 b0 = *(const short8*)&bs[(wc * 32 + l16) * 64 + cswz];
      const short8 b1 = *(const short8*)&bs[(wc * 32 + 16 + l16) * 64 + cswz];
#pragma unroll
      for (int mq = 0; mq < 2; ++mq) {
        short8 af[4];
#pragma unroll
        for (int i = 0; i < 4; ++i)
          af[i] = *(const short8*)&as[(wr * 128 + (mq * 4 + i) * 16 + l16) * 64 + cswz];
        __builtin_amdgcn_s_setprio(1);
#pragma unroll
        for (int i = 0; i < 4; ++i) {
          acc[mq * 4 + i][0] = MFMA32(af[i], b0, acc[mq * 4 + i][0]);
          acc[mq * 4 + i][1] = MFMA32(af[i], b1, acc[mq * 4 + i][1]);
        }
        __builtin_amdgcn_s_setprio(0);
      }
    }

    __builtin_amdgcn_s_barrier();   // all waves done reading slot st
    if (t + 3 < 16) STAGE6(st, t + 3);
  }
#undef STAGEA
#undef STAGEB
#undef STAGE6

  // epilogue: qkv swizzle (formulas identical to R5, new geometry)
#pragma unroll
  for (int mt = 0; mt < 8; ++mt) {
#pragma unroll
    for (int nt = 0; nt < 2; ++nt) {
      const int col = col0 + wc * 32 + nt * 16 + l16;
      const int which = col >> 10;          // 0=q 1=k 2=v (block-uniform, 1024%128==0)
      const int hc = (col & 1023) >> 6;
      const int d = col & 63;
#pragma unroll
      for (int r = 0; r < 4; ++r) {
        const int row = row0 + wr * 128 + mt * 16 + quad * 4 + r;
        const float val = acc[mt][nt][r];
        const int b = row >> 11;
        const int nn = row & 2047;
        const size_t hb = (size_t)(b * 16 + hc) * 131072;
        if (which == 0) {
          // fold softmax scale (1/8) and log2(e) into Q
          Qh[hb + (size_t)nn * 64 + d] = f32_to_bf16(val * 0.1803368801111244f);
        } else if (which == 1) {
          const uint16_t bv = f32_to_bf16(val);
          // K: 16x16x32 A-frag order [jt][st][kc][lane=qd*16+j16][e8]
          const int jt = nn >> 6, st2 = (nn >> 4) & 3, j16 = nn & 15;
          const int kc = d >> 5, qd = (d >> 3) & 3, e = d & 7;
          Kh[hb + jt * 4096 + st2 * 1024 + kc * 512 + (qd * 16 + j16) * 8 + e] = bv;
        } else {
          const uint16_t bv = f32_to_bf16(val);
          // V: 16x16x16 B-frag order [jt][st][tth][lane=qv*16+d16][ttl][e4]
          const int jt = nn >> 6, j = nn & 63;
          const int st2 = j >> 4, qv = (j >> 2) & 3, e = j & 3;
          const int tt = d >> 4, d16 = d & 15;
          Vh[hb + jt * 4096 + ((st2 * 2 + (tt >> 1)) * 64 + qv * 16 + d16) * 8 +
             (tt & 1) * 4 + e] = bv;
        }
      }
    }
  }
}

// ---------------- flash attention, LDS-shared KV (R3, confirmed 54.5 us) ----------------
__global__ __launch_bounds__(256, 2) void attn_kernel(
    const uint16_t* __restrict__ Qh, const uint16_t* __restrict__ Kh,
    const uint16_t* __restrict__ Vh, uint16_t* __restrict__ out) {
  __shared__ __align__(16) uint16_t Ks[2][4096];
  __shared__ __align__(16) uint16_t Vs[2][4096];
  const int tid = threadIdx.x;
  const int wave = tid >> 6;
  const int lane = tid & 63;
  const int quad = lane >> 4;
  const int l16 = lane & 15;
  const int bx = blockIdx.x;
  const int it = bx & 15;
  const int h = (bx >> 4) & 15;
  const int ib = bx >> 8;
  const int i0 = it * 128 + wave * 32;
  const size_t hb = (size_t)(ib * 16 + h) * 131072;

  // Q fragments (B-operand of S^T MFMA): lane l16 = q-row, k = quad*8+e
  short8 qf[2][2];
#pragma unroll
  for (int m = 0; m < 2; ++m)
#pragma unroll
    for (int kc = 0; kc < 2; ++kc)
      qf[m][kc] = *(const short8*)(Qh + hb + (size_t)(i0 + m * 16 + l16) * 64 + kc * 32 + quad * 8);

  f32x4 o[2][4], o4[2];
#pragma unroll
  for (int m = 0; m < 2; ++m) {
    o4[m] = (f32x4){0.f, 0.f, 0.f, 0.f};
#pragma unroll
    for (int t = 0; t < 4; ++t) o[m][t] = (f32x4){0.f, 0.f, 0.f, 0.f};
  }

  const bf16x4 ones4 = {(short)0x3F80, (short)0x3F80, (short)0x3F80, (short)0x3F80};

  // staging: this wave stages elems [wave*1024, wave*1024+1024) of each tile
  const uint16_t* gK = Kh + hb + wave * 1024 + lane * 8;
  const uint16_t* gV = Vh + hb + wave * 1024 + lane * 8;
  const int so = wave * 1024;

  // prologue: stage tile 0 into buf 0
  load_lds16(gK, &Ks[0][so]);
  load_lds16(gK + 512, &Ks[0][so + 512]);
  load_lds16(gV, &Vs[0][so]);
  load_lds16(gV + 512, &Vs[0][so + 512]);
  __syncthreads();

#pragma unroll 2
  for (int t = 0; t < 32; ++t) {
    const int cur = t & 1;
    // stage tile t+1 into the other buffer (hidden under this tile's compute)
    if (t < 31) {
      const size_t goff = (size_t)(t + 1) * 4096;
      load_lds16(gK + goff, &Ks[cur ^ 1][so]);
      load_lds16(gK + goff + 512, &Ks[cur ^ 1][so + 512]);
      load_lds16(gV + goff, &Vs[cur ^ 1][so]);
      load_lds16(gV + goff + 512, &Vs[cur ^ 1][so + 512]);
    }

    // K frags from LDS (same frag order as the global layout)
    short8 kf[8];
#pragma unroll
    for (int i = 0; i < 8; ++i) kf[i] = *(const short8*)&Ks[cur][i * 512 + lane * 8];

    // S^T = K . Q^T : lane holds q-row l16, j = st*16 + quad*4 + r
    f32x4 s[2][4];
#pragma unroll
    for (int m = 0; m < 2; ++m)
#pragma unroll
      for (int st = 0; st < 4; ++st) {
        f32x4 sc = (f32x4){0.f, 0.f, 0.f, 0.f};
        sc = MFMA32(kf[st * 2 + 0], qf[m][0], sc);
        sc = MFMA32(kf[st * 2 + 1], qf[m][1], sc);
        s[m][st] = sc;
      }

    // V frags (issue ds_reads while exp2 runs)
    short8 v8[8];
#pragma unroll
    for (int i = 0; i < 8; ++i) v8[i] = *(const short8*)&Vs[cur][i * 512 + lane * 8];

    // P = exp2(s), packed straight into 16x16x16 A-frags (k = quad*4 + e)
    bf16x4 p4[2][4];
#pragma unroll
    for (int m = 0; m < 2; ++m)
#pragma unroll
      for (int st = 0; st < 4; ++st) {
        bf16x4 p;
#pragma unroll
        for (int r = 0; r < 4; ++r)
          p[r] = (short)f32_to_bf16_fast(__builtin_amdgcn_exp2f(s[m][st][r]));
        p4[m][st] = p;
      }

    // O += P V (16x16x16), row sums via ones-column
#pragma unroll
    for (int st = 0; st < 4; ++st) {
#pragma unroll
      for (int m = 0; m < 2; ++m) {
        o4[m] = MFMA16(p4[m][st], ones4, o4[m]);
#pragma unroll
        for (int tth = 0; tth < 2; ++tth) {
          const short8 w = v8[st * 2 + tth];
          const bf16x4 vlo = {w[0], w[1], w[2], w[3]};
          const bf16x4 vhi = {w[4], w[5], w[6], w[7]};
          o[m][tth * 2 + 0] = MFMA16(p4[m][st], vlo, o[m][tth * 2 + 0]);
          o[m][tth * 2 + 1] = MFMA16(p4[m][st], vhi, o[m][tth * 2 + 1]);
        }
      }
    }

    __syncthreads();
  }

  // epilogue: O /= l, store bf16 [B*2048][1024]
#pragma unroll
  for (int m = 0; m < 2; ++m)
#pragma unroll
    for (int r = 0; r < 4; ++r) {
      const float inv = 1.0f / o4[m][r];
      const int row = i0 + m * 16 + quad * 4 + r;
      const size_t obase = (size_t)(ib * 2048 + row) * 1024 + h * 64;
#pragma unroll
      for (int tt = 0; tt < 4; ++tt)
        out[obase + tt * 16 + l16] = f32_to_bf16(o[m][tt][r] * inv);
    }
}

// ---------------- launch ----------------
extern "C" void kernel_launch(void* const* d_in, const int* in_sizes, int n_in,
                              void* d_out, int out_size, void* d_ws, size_t ws_size,
                              hipStream_t stream) {
  const float* x = (const float*)d_in[0];     // [2,2048,1024]
  const float* Wqkv = (const float*)d_in[1];  // [3072,1024]
  const float* Wout = (const float*)d_in[2];  // [1024,1024]
  const float* bout = (const float*)d_in[3];  // [1024]

  uint16_t* xb = (uint16_t*)d_ws;                       // 4096*1024
  uint16_t* wqkvb = xb + (size_t)4096 * 1024;           // 3072*1024
  uint16_t* woutb = wqkvb + (size_t)3072 * 1024;        // 1024*1024
  uint16_t* qh = woutb + (size_t)1024 * 1024;           // 32 heads * 131072
  uint16_t* kh = qh + (size_t)32 * 131072;
  uint16_t* vh = kh + (size_t)32 * 131072;
  uint16_t* attnb = vh + (size_t)32 * 131072;           // 4096*1024

  cvt3_kernel<<<8192, 256, 0, stream>>>(x, Wqkv, Wout, xb, wqkvb, woutb);

  gemm_qkv_kernel<<<dim3(4096 / 256, 3072 / 128), 512, 0, stream>>>(
      xb, wqkvb, qh, kh, vh);

  attn_kernel<<<512, 256, 0, stream>>>(qh, kh, vh, attnb);

  dim3 g2(4096 / 128, 1024 / 128);
  gemm_abt_kernel<<<g2, dim3(256), 0, stream>>>(
      attnb, woutb, (float*)d_out, bout, 4096, 1024, 1024);
}

// Round 7
// 184.952 us; speedup vs baseline: 1.1153x; 1.1153x over previous
//
#include <hip/hip_runtime.h>
#include <stdint.h>

typedef __attribute__((ext_vector_type(8))) short short8;
typedef __attribute__((ext_vector_type(4))) short bf16x4;
typedef __attribute__((ext_vector_type(4))) float f32x4;

#define MFMA32(a, b, c) __builtin_amdgcn_mfma_f32_16x16x32_bf16((a), (b), (c), 0, 0, 0)
#define MFMA16(a, b, c) __builtin_amdgcn_mfma_f32_16x16x16bf16_1k((a), (b), (c), 0, 0, 0)

__device__ __forceinline__ uint16_t f32_to_bf16(float f) {
  union { float f; uint32_t u; } v; v.f = f;
  uint32_t u = v.u;
  u += 0x7FFFu + ((u >> 16) & 1u);   // RTNE
  return (uint16_t)(u >> 16);
}
__device__ __forceinline__ uint16_t f32_to_bf16_fast(float f) {
  union { float f; uint32_t u; } v; v.f = f;
  return (uint16_t)((v.u + 0x8000u) >> 16);   // round-half-up (P only)
}

__device__ __forceinline__ void load_lds16(const uint16_t* g, uint16_t* l) {
  __builtin_amdgcn_global_load_lds(
      (const __attribute__((address_space(1))) uint32_t*)g,
      (__attribute__((address_space(3))) uint32_t*)l, 16, 0, 0);
}

// ---------------- fused f32 -> bf16 conversion (x, Wqkv, Wout) ----------------
__global__ __launch_bounds__(256) void cvt3_kernel(
    const float* __restrict__ x, const float* __restrict__ w1,
    const float* __restrict__ w2, uint16_t* __restrict__ xb,
    uint16_t* __restrict__ w1b, uint16_t* __restrict__ w2b) {
  const int i = blockIdx.x * 256 + threadIdx.x;  // 2,097,152 float4 total
  const float4* src;
  ushort4* dst;
  int off;
  if (i < 1048576) { src = (const float4*)x;  dst = (ushort4*)xb;  off = i; }
  else if (i < 1835008) { src = (const float4*)w1; dst = (ushort4*)w1b; off = i - 1048576; }
  else { src = (const float4*)w2; dst = (ushort4*)w2b; off = i - 1835008; }
  const float4 v = src[off];
  ushort4 o;
  o.x = f32_to_bf16(v.x);
  o.y = f32_to_bf16(v.y);
  o.z = f32_to_bf16(v.z);
  o.w = f32_to_bf16(v.w);
  dst[off] = o;
}

// ---------------- QKV GEMM: 128x128 tile, BK=64, single-buffer serial ----------------
// R4-R6 lesson: deep-pipelined 512-thr/128KB-LDS structures (8-phase drain0,
// 3-slot counted vmcnt) both LOSE to this serial shape (54-57 vs 43.7 us):
// at 1 block/CU with barrier-locked waves there is no co-resident work to hide
// bubbles; the 128x128/16-32KB shape gets 3 blocks/CU of free inter-block
// overlap (m114). Changes vs the proven BK=32 version, each with a mechanism:
//  - BK=64: same MFMA/ds_read/stage totals, HALF the barrier-drain events.
//  - R5's proven XOR swizzle (measured 0 conflicts): BK=32's 64B row stride
//    was an 8-way bank conflict on ds_read_b128; [128][64] swizzled is 0-way.
//    Write side: global source chunk (lane&7)^(row&7); read side:
//    chunk (ks*4+quad)^(l16&7). Both-sides-or-neither (rule #21).
__global__ __launch_bounds__(256) void gemm_qkv_kernel(
    const uint16_t* __restrict__ A, const uint16_t* __restrict__ Bt,
    uint16_t* __restrict__ Qh, uint16_t* __restrict__ Kh, uint16_t* __restrict__ Vh) {
  __shared__ __align__(16) uint16_t As[128 * 64];   // 16 KB
  __shared__ __align__(16) uint16_t Bs[128 * 64];   // 16 KB
  const int tid = threadIdx.x;
  const int wave = tid >> 6;
  const int lane = tid & 63;
  const int quad = lane >> 4;
  const int l16 = lane & 15;
  const int row0 = blockIdx.x * 128;
  const int col0 = blockIdx.y * 128;
  const int wm = (wave >> 1) * 64;
  const int wn = (wave & 1) * 64;
  const int K = 1024;

  f32x4 acc[4][4];
#pragma unroll
  for (int a = 0; a < 4; ++a)
#pragma unroll
    for (int b = 0; b < 4; ++b) acc[a][b] = (f32x4){0.f, 0.f, 0.f, 0.f};

  // staging: wave covers rows [wave*32, wave*32+32), 4 loads of 8 rows each;
  // 8 lanes x 16B = 128B per row; source chunk pre-swizzled (T2 write side).
  const int swz8 = ((lane & 7) ^ ((lane >> 3) & 7)) * 8;
  const uint16_t* gA = A + (size_t)(row0 + wave * 32 + (lane >> 3)) * K + swz8;
  const uint16_t* gB = Bt + (size_t)(col0 + wave * 32 + (lane >> 3)) * K + swz8;

  for (int k0 = 0; k0 < K; k0 += 64) {
#pragma unroll
    for (int s = 0; s < 4; ++s) {
      load_lds16(gA + (size_t)s * 8 * K + k0, &As[(wave * 32 + s * 8) * 64]);
      load_lds16(gB + (size_t)s * 8 * K + k0, &Bs[(wave * 32 + s * 8) * 64]);
    }
    __syncthreads();
#pragma unroll
    for (int ks = 0; ks < 2; ++ks) {
      // read swizzle cancels the source pre-swizzle (frag row &7 == l16&7)
      const int cswz = (((ks * 4 + quad) ^ (l16 & 7)) * 8);
      short8 af[4], bf[4];
#pragma unroll
      for (int mt = 0; mt < 4; ++mt)
        af[mt] = *(const short8*)&As[(wm + mt * 16 + l16) * 64 + cswz];
#pragma unroll
      for (int nt = 0; nt < 4; ++nt)
        bf[nt] = *(const short8*)&Bs[(wn + nt * 16 + l16) * 64 + cswz];
#pragma unroll
      for (int mt = 0; mt < 4; ++mt)
#pragma unroll
        for (int nt = 0; nt < 4; ++nt)
          acc[mt][nt] = MFMA32(af[mt], bf[nt], acc[mt][nt]);
    }
    __syncthreads();
  }

  // epilogue: qkv swizzle (verbatim from the proven R3 MODE-1 epilogue)
#pragma unroll
  for (int mt = 0; mt < 4; ++mt) {
#pragma unroll
    for (int nt = 0; nt < 4; ++nt) {
      const int col = col0 + wn + nt * 16 + l16;
      const int which = col >> 10;          // 0=q 1=k 2=v (block-uniform)
      const int hc = (col & 1023) >> 6;
      const int d = col & 63;
#pragma unroll
      for (int r = 0; r < 4; ++r) {
        const int row = row0 + wm + mt * 16 + quad * 4 + r;
        const float val = acc[mt][nt][r];
        const int b = row >> 11;
        const int nn = row & 2047;
        const size_t hb = (size_t)(b * 16 + hc) * 131072;
        if (which == 0) {
          // fold softmax scale (1/8) and log2(e) into Q
          Qh[hb + (size_t)nn * 64 + d] = f32_to_bf16(val * 0.1803368801111244f);
        } else if (which == 1) {
          const uint16_t bv = f32_to_bf16(val);
          // K: 16x16x32 A-frag order [jt][st][kc][lane=qd*16+j16][e8]
          const int jt = nn >> 6, st = (nn >> 4) & 3, j16 = nn & 15;
          const int kc = d >> 5, qd = (d >> 3) & 3, e = d & 7;
          Kh[hb + jt * 4096 + st * 1024 + kc * 512 + (qd * 16 + j16) * 8 + e] = bv;
        } else {
          const uint16_t bv = f32_to_bf16(val);
          // V: 16x16x16 B-frag order [jt][st][tth][lane=qv*16+d16][ttl][e4]
          const int jt = nn >> 6, j = nn & 63;
          const int st = j >> 4, qv = (j >> 2) & 3, e = j & 3;
          const int tt = d >> 4, d16 = d & 15;
          Vh[hb + jt * 4096 + ((st * 2 + (tt >> 1)) * 64 + qv * 16 + d16) * 8 +
             (tt & 1) * 4 + e] = bv;
        }
      }
    }
  }
}

// ---------------- output-proj GEMM: 128x64 tile, BK=64, single-buffer serial ----------------
// R6 realization: the old 128x128 gemm2 grid was 256 blocks = 1 block/CU =
// 1 wave/SIMD -> zero latency hiding on the serial stage->drain->compute loop.
// 128x64 tile doubles the grid to 512 (2 blocks/CU) and keeps the proven shape.
__global__ __launch_bounds__(256) void gemm_out_kernel(
    const uint16_t* __restrict__ A, const uint16_t* __restrict__ Bt,
    float* __restrict__ Cf, const float* __restrict__ bias) {
  __shared__ __align__(16) uint16_t As[128 * 64];   // 16 KB
  __shared__ __align__(16) uint16_t Bs[64 * 64];    // 8 KB
  const int tid = threadIdx.x;
  const int wave = tid >> 6;
  const int lane = tid & 63;
  const int quad = lane >> 4;
  const int l16 = lane & 15;
  const int row0 = blockIdx.x * 128;
  const int col0 = blockIdx.y * 64;
  const int wm = (wave >> 1) * 64;
  const int wn = (wave & 1) * 32;
  const int K = 1024;
  const int N = 1024;

  f32x4 acc[4][2];
#pragma unroll
  for (int a = 0; a < 4; ++a)
#pragma unroll
    for (int b = 0; b < 2; ++b) acc[a][b] = (f32x4){0.f, 0.f, 0.f, 0.f};

  const int swz8 = ((lane & 7) ^ ((lane >> 3) & 7)) * 8;
  const uint16_t* gA = A + (size_t)(row0 + wave * 32 + (lane >> 3)) * K + swz8;
  const uint16_t* gB = Bt + (size_t)(col0 + wave * 16 + (lane >> 3)) * K + swz8;

  for (int k0 = 0; k0 < K; k0 += 64) {
#pragma unroll
    for (int s = 0; s < 4; ++s)
      load_lds16(gA + (size_t)s * 8 * K + k0, &As[(wave * 32 + s * 8) * 64]);
#pragma unroll
    for (int s = 0; s < 2; ++s)
      load_lds16(gB + (size_t)s * 8 * K + k0, &Bs[(wave * 16 + s * 8) * 64]);
    __syncthreads();
#pragma unroll
    for (int ks = 0; ks < 2; ++ks) {
      const int cswz = (((ks * 4 + quad) ^ (l16 & 7)) * 8);
      short8 af[4], bf[2];
#pragma unroll
      for (int mt = 0; mt < 4; ++mt)
        af[mt] = *(const short8*)&As[(wm + mt * 16 + l16) * 64 + cswz];
#pragma unroll
      for (int nt = 0; nt < 2; ++nt)
        bf[nt] = *(const short8*)&Bs[(wn + nt * 16 + l16) * 64 + cswz];
#pragma unroll
      for (int mt = 0; mt < 4; ++mt)
#pragma unroll
        for (int nt = 0; nt < 2; ++nt)
          acc[mt][nt] = MFMA32(af[mt], bf[nt], acc[mt][nt]);
    }
    __syncthreads();
  }

#pragma unroll
  for (int mt = 0; mt < 4; ++mt) {
#pragma unroll
    for (int nt = 0; nt < 2; ++nt) {
      const int col = col0 + wn + nt * 16 + l16;
#pragma unroll
      for (int r = 0; r < 4; ++r) {
        const int row = row0 + wm + mt * 16 + quad * 4 + r;
        Cf[(size_t)row * N + col] = acc[mt][nt][r] + bias[col];
      }
    }
  }
}

// ---------------- flash attention, LDS-shared KV (R3, confirmed 54.5 us) ----------------
__global__ __launch_bounds__(256, 2) void attn_kernel(
    const uint16_t* __restrict__ Qh, const uint16_t* __restrict__ Kh,
    const uint16_t* __restrict__ Vh, uint16_t* __restrict__ out) {
  __shared__ __align__(16) uint16_t Ks[2][4096];
  __shared__ __align__(16) uint16_t Vs[2][4096];
  const int tid = threadIdx.x;
  const int wave = tid >> 6;
  const int lane = tid & 63;
  const int quad = lane >> 4;
  const int l16 = lane & 15;
  const int bx = blockIdx.x;
  const int it = bx & 15;
  const int h = (bx >> 4) & 15;
  const int ib = bx >> 8;
  const int i0 = it * 128 + wave * 32;
  const size_t hb = (size_t)(ib * 16 + h) * 131072;

  // Q fragments (B-operand of S^T MFMA): lane l16 = q-row, k = quad*8+e
  short8 qf[2][2];
#pragma unroll
  for (int m = 0; m < 2; ++m)
#pragma unroll
    for (int kc = 0; kc < 2; ++kc)
      qf[m][kc] = *(const short8*)(Qh + hb + (size_t)(i0 + m * 16 + l16) * 64 + kc * 32 + quad * 8);

  f32x4 o[2][4], o4[2];
#pragma unroll
  for (int m = 0; m < 2; ++m) {
    o4[m] = (f32x4){0.f, 0.f, 0.f, 0.f};
#pragma unroll
    for (int t = 0; t < 4; ++t) o[m][t] = (f32x4){0.f, 0.f, 0.f, 0.f};
  }

  const bf16x4 ones4 = {(short)0x3F80, (short)0x3F80, (short)0x3F80, (short)0x3F80};

  // staging: this wave stages elems [wave*1024, wave*1024+1024) of each tile
  const uint16_t* gK = Kh + hb + wave * 1024 + lane * 8;
  const uint16_t* gV = Vh + hb + wave * 1024 + lane * 8;
  const int so = wave * 1024;

  // prologue: stage tile 0 into buf 0
  load_lds16(gK, &Ks[0][so]);
  load_lds16(gK + 512, &Ks[0][so + 512]);
  load_lds16(gV, &Vs[0][so]);
  load_lds16(gV + 512, &Vs[0][so + 512]);
  __syncthreads();

#pragma unroll 2
  for (int t = 0; t < 32; ++t) {
    const int cur = t & 1;
    // stage tile t+1 into the other buffer (hidden under this tile's compute)
    if (t < 31) {
      const size_t goff = (size_t)(t + 1) * 4096;
      load_lds16(gK + goff, &Ks[cur ^ 1][so]);
      load_lds16(gK + goff + 512, &Ks[cur ^ 1][so + 512]);
      load_lds16(gV + goff, &Vs[cur ^ 1][so]);
      load_lds16(gV + goff + 512, &Vs[cur ^ 1][so + 512]);
    }

    // K frags from LDS (same frag order as the global layout)
    short8 kf[8];
#pragma unroll
    for (int i = 0; i < 8; ++i) kf[i] = *(const short8*)&Ks[cur][i * 512 + lane * 8];

    // S^T = K . Q^T : lane holds q-row l16, j = st*16 + quad*4 + r
    f32x4 s[2][4];
#pragma unroll
    for (int m = 0; m < 2; ++m)
#pragma unroll
      for (int st = 0; st < 4; ++st) {
        f32x4 sc = (f32x4){0.f, 0.f, 0.f, 0.f};
        sc = MFMA32(kf[st * 2 + 0], qf[m][0], sc);
        sc = MFMA32(kf[st * 2 + 1], qf[m][1], sc);
        s[m][st] = sc;
      }

    // V frags (issue ds_reads while exp2 runs)
    short8 v8[8];
#pragma unroll
    for (int i = 0; i < 8; ++i) v8[i] = *(const short8*)&Vs[cur][i * 512 + lane * 8];

    // P = exp2(s), packed straight into 16x16x16 A-frags (k = quad*4 + e)
    bf16x4 p4[2][4];
#pragma unroll
    for (int m = 0; m < 2; ++m)
#pragma unroll
      for (int st = 0; st < 4; ++st) {
        bf16x4 p;
#pragma unroll
        for (int r = 0; r < 4; ++r)
          p[r] = (short)f32_to_bf16_fast(__builtin_amdgcn_exp2f(s[m][st][r]));
        p4[m][st] = p;
      }

    // O += P V (16x16x16), row sums via ones-column
#pragma unroll
    for (int st = 0; st < 4; ++st) {
#pragma unroll
      for (int m = 0; m < 2; ++m) {
        o4[m] = MFMA16(p4[m][st], ones4, o4[m]);
#pragma unroll
        for (int tth = 0; tth < 2; ++tth) {
          const short8 w = v8[st * 2 + tth];
          const bf16x4 vlo = {w[0], w[1], w[2], w[3]};
          const bf16x4 vhi = {w[4], w[5], w[6], w[7]};
          o[m][tth * 2 + 0] = MFMA16(p4[m][st], vlo, o[m][tth * 2 + 0]);
          o[m][tth * 2 + 1] = MFMA16(p4[m][st], vhi, o[m][tth * 2 + 1]);
        }
      }
    }

    __syncthreads();
  }

  // epilogue: O /= l, store bf16 [B*2048][1024]
#pragma unroll
  for (int m = 0; m < 2; ++m)
#pragma unroll
    for (int r = 0; r < 4; ++r) {
      const float inv = 1.0f / o4[m][r];
      const int row = i0 + m * 16 + quad * 4 + r;
      const size_t obase = (size_t)(ib * 2048 + row) * 1024 + h * 64;
#pragma unroll
      for (int tt = 0; tt < 4; ++tt)
        out[obase + tt * 16 + l16] = f32_to_bf16(o[m][tt][r] * inv);
    }
}

// ---------------- launch ----------------
extern "C" void kernel_launch(void* const* d_in, const int* in_sizes, int n_in,
                              void* d_out, int out_size, void* d_ws, size_t ws_size,
                              hipStream_t stream) {
  const float* x = (const float*)d_in[0];     // [2,2048,1024]
  const float* Wqkv = (const float*)d_in[1];  // [3072,1024]
  const float* Wout = (const float*)d_in[2];  // [1024,1024]
  const float* bout = (const float*)d_in[3];  // [1024]

  uint16_t* xb = (uint16_t*)d_ws;                       // 4096*1024
  uint16_t* wqkvb = xb + (size_t)4096 * 1024;           // 3072*1024
  uint16_t* woutb = wqkvb + (size_t)3072 * 1024;        // 1024*1024
  uint16_t* qh = woutb + (size_t)1024 * 1024;           // 32 heads * 131072
  uint16_t* kh = qh + (size_t)32 * 131072;
  uint16_t* vh = kh + (size_t)32 * 131072;
  uint16_t* attnb = vh + (size_t)32 * 131072;           // 4096*1024

  cvt3_kernel<<<8192, 256, 0, stream>>>(x, Wqkv, Wout, xb, wqkvb, woutb);

  gemm_qkv_kernel<<<dim3(4096 / 128, 3072 / 128), 256, 0, stream>>>(
      xb, wqkvb, qh, kh, vh);

  attn_kernel<<<512, 256, 0, stream>>>(qh, kh, vh, attnb);

  gemm_out_kernel<<<dim3(4096 / 128, 1024 / 64), 256, 0, stream>>>(
      attnb, woutb, (float*)d_out, bout);
}